// Round 7
// baseline (991.594 us; speedup 1.0000x reference)
//
#include <hip/hip_runtime.h>

// ---------------------------------------------------------------------------
// Talking-heads attention. B=2, N=M=2048, D=1024, H=16, dh=64.
// R11: R10 (qk_exp K-resident, BK=64 GEMMs) with talk_ln reverted to the
// R9-proven 2 j/thread register shape (p[16]+t[16] per j => ~80-100 VGPR,
// no spill) under __launch_bounds__(256,4) (cap 128 regs). R10's 4 j/thread
// variant spilled its 64-float accumulator array (FETCH+WRITE 584MB vs 128).
// ---------------------------------------------------------------------------

typedef __attribute__((ext_vector_type(8))) short short8;
typedef __attribute__((ext_vector_type(4))) short short4v;
typedef __attribute__((ext_vector_type(4))) float float4v;
typedef unsigned short u16;

#define MFMA16(a, b, c) __builtin_amdgcn_mfma_f32_16x16x32_bf16((a), (b), (c), 0, 0, 0)

__device__ inline u16 f2bf(float f) {  // RNE f32->bf16 (inputs finite)
  unsigned u = __float_as_uint(f);
  u += 0x7FFFu + ((u >> 16) & 1u);
  return (u16)(u >> 16);
}
__device__ inline float bf2f(u16 u) {
  return __uint_as_float(((unsigned)u) << 16);
}
__device__ inline float fexp2(float x) { return __builtin_amdgcn_exp2f(x); }

// ---------------------------- cast kernel ----------------------------------
__global__ __launch_bounds__(256) void cast_bf16(const float* __restrict__ in,
                                                 u16* __restrict__ out, int n) {
  int i = (blockIdx.x * 256 + threadIdx.x) * 8;
  if (i + 8 > n) return;
  float4v f0 = *(const float4v*)(in + i);
  float4v f1 = *(const float4v*)(in + i + 4);
  short8 o;
  o[0] = (short)f2bf(f0[0]); o[1] = (short)f2bf(f0[1]);
  o[2] = (short)f2bf(f0[2]); o[3] = (short)f2bf(f0[3]);
  o[4] = (short)f2bf(f1[0]); o[5] = (short)f2bf(f1[1]);
  o[6] = (short)f2bf(f1[2]); o[7] = (short)f2bf(f1[3]);
  *(short8*)(out + i) = o;
}

// ------------------------ projection GEMM (BK=64) --------------------------
template <int MODE>
__global__ __launch_bounds__(256, 4) void gemm_bt(const u16* __restrict__ A,
                                                  const u16* __restrict__ W,
                                                  u16* __restrict__ out0,
                                                  u16* __restrict__ out1) {
  __shared__ u16 As[64][72];
  __shared__ u16 Ws[64][72];
  const int t = threadIdx.x;
  const int wave = t >> 6, l = t & 63, l15 = l & 15, lq = l >> 4;
  const int r0 = blockIdx.x * 64, c0 = blockIdx.y * 64;
  const int srow = t >> 2, sch = t & 3;
  const u16* ag = A + (r0 + srow) * 1024 + sch * 16;
  const u16* wg = W + (c0 + srow) * 1024 + sch * 16;

  float4v acc[4];
#pragma unroll
  for (int i = 0; i < 4; ++i) acc[i] = (float4v){0.f, 0.f, 0.f, 0.f};

  short8 av0 = *(const short8*)ag, av1 = *(const short8*)(ag + 8);
  short8 wv0 = *(const short8*)wg, wv1 = *(const short8*)(wg + 8);
  for (int kt = 0; kt < 16; ++kt) {
    __syncthreads();
    *(short8*)&As[srow][sch * 16] = av0;
    *(short8*)&As[srow][sch * 16 + 8] = av1;
    *(short8*)&Ws[srow][sch * 16] = wv0;
    *(short8*)&Ws[srow][sch * 16 + 8] = wv1;
    __syncthreads();
    if (kt < 15) {
      const u16* an = ag + (kt + 1) * 64;
      const u16* wn = wg + (kt + 1) * 64;
      av0 = *(const short8*)an; av1 = *(const short8*)(an + 8);
      wv0 = *(const short8*)wn; wv1 = *(const short8*)(wn + 8);
    }
    short8 af0 = *(const short8*)&As[wave * 16 + l15][lq * 8];
    short8 af1 = *(const short8*)&As[wave * 16 + l15][32 + lq * 8];
#pragma unroll
    for (int fn = 0; fn < 4; ++fn) {
      short8 bf0 = *(const short8*)&Ws[fn * 16 + l15][lq * 8];
      short8 bf1 = *(const short8*)&Ws[fn * 16 + l15][32 + lq * 8];
      acc[fn] = MFMA16(af0, bf0, acc[fn]);
      acc[fn] = MFMA16(af1, bf1, acc[fn]);
    }
  }
#pragma unroll
  for (int fn = 0; fn < 4; ++fn) {
#pragma unroll
    for (int r = 0; r < 4; ++r) {
      int row = r0 + wave * 16 + lq * 4 + r;
      int col = c0 + fn * 16 + l15;
      int b = row >> 11, n = row & 2047;
      float v = acc[fn][r];
      if (MODE == 0) {
        // dh^-0.5 * log2(e): softmax done in base 2 (v_exp_f32 is 2^x)
        v *= 0.125f * 1.44269504088896f;
        int h = col >> 6, d = col & 63;
        out0[(((b * 16 + h) * 2048 + n) << 6) + d] = f2bf(v);
      } else {
        if (col < 1024) {
          int h = col >> 6, d = col & 63;
          out0[(((b * 16 + h) * 2048 + n) << 6) + d] = f2bf(v);
        } else {
          int cc = col - 1024;
          int h = cc >> 6, d = cc & 63;
          out1[(((b * 16 + h) * 2048 + n) << 6) + d] = f2bf(v);
        }
      }
    }
  }
}

// --------------------------- V transpose -----------------------------------
__global__ __launch_bounds__(256) void transpose_v(const u16* __restrict__ vh,
                                                   u16* __restrict__ vt) {
  __shared__ u16 tile[64][72];
  const int t = threadIdx.x;
  const int j0 = blockIdx.x * 64, h = blockIdx.y, b = blockIdx.z;
  const u16* src = vh + (((b * 16 + h) * 2048 + j0) << 6);
  int row = t >> 2, c = t & 3;
  short8 v0 = *(const short8*)(src + row * 64 + c * 8);
  short8 v1 = *(const short8*)(src + row * 64 + (c + 4) * 8);
  *(short8*)&tile[row][c * 8] = v0;
  *(short8*)&tile[row][(c + 4) * 8] = v1;
  __syncthreads();
  int d = t >> 2, jc = t & 3;
  short8 o0, o1;
#pragma unroll
  for (int jj = 0; jj < 8; ++jj) o0[jj] = (short)tile[jc * 16 + jj][d];
#pragma unroll
  for (int jj = 0; jj < 8; ++jj) o1[jj] = (short)tile[jc * 16 + 8 + jj][d];
  u16* dst = vt + ((b * 16 + h) * 64 + d) * 2048 + j0 + jc * 16;
  *(short8*)dst = o0;
  *(short8*)(dst + 8) = o1;
}

// ------------------------ A: QK^T -> E = 2^S (v2) --------------------------
// grid (ib=8, jm=8, bh=32) per quarter, 256 threads (4 waves).
// Wave owns a 64-j strip: K fragments loaded ONCE into 32 VGPRs, then loops
// 4 i-subtiles of 16 rows against them (2 Q loads + 8 MFMA + 16 exp + 4
// stores per iter). Row sums (of bf16-rounded E) atomicAdd'ed to lsum.
__global__ __launch_bounds__(256, 6) void qk_exp(const u16* __restrict__ qh,
                                                 const u16* __restrict__ kh,
                                                 u16* __restrict__ E,
                                                 float* __restrict__ lsum,
                                                 int i_base) {
  const int t = threadIdx.x;
  const int w = t >> 6, l = t & 63, l15 = l & 15, lq = l >> 4;
  const int ib = blockIdx.x;   // i-group of 64 (quarter-local)
  const int jm = blockIdx.y;   // j-macro of 256
  const int bh = blockIdx.z;
  const int j0 = jm * 256 + w * 64;  // wave's j strip

  const u16* kb = kh + (size_t)(bh * 2048 + j0 + l15) * 64 + lq * 8;
  short8 k0 = *(const short8*)(kb);
  short8 k1 = *(const short8*)(kb + 32);
  short8 k2 = *(const short8*)(kb + 1024);
  short8 k3 = *(const short8*)(kb + 1024 + 32);
  short8 k4 = *(const short8*)(kb + 2048);
  short8 k5 = *(const short8*)(kb + 2048 + 32);
  short8 k6 = *(const short8*)(kb + 3072);
  short8 k7 = *(const short8*)(kb + 3072 + 32);

#pragma unroll 1
  for (int is = 0; is < 4; ++is) {
    const int i0 = ib * 64 + is * 16;  // quarter-local i of this subtile
    const u16* qb = qh + (size_t)(bh * 2048 + i_base + i0 + l15) * 64 + lq * 8;
    short8 qf0 = *(const short8*)qb;
    short8 qf1 = *(const short8*)(qb + 32);
    float4v s0 = {0.f, 0.f, 0.f, 0.f}, s1 = s0, s2 = s0, s3 = s0;
    s0 = MFMA16(k0, qf0, s0); s0 = MFMA16(k1, qf1, s0);
    s1 = MFMA16(k2, qf0, s1); s1 = MFMA16(k3, qf1, s1);
    s2 = MFMA16(k4, qf0, s2); s2 = MFMA16(k5, qf1, s2);
    s3 = MFMA16(k6, qf0, s3); s3 = MFMA16(k7, qf1, s3);
    // lane holds E[i = i0+l15][j = j0 + fn*16 + lq*4 + r]
    u16* eb = E + ((size_t)(bh * 512 + i0 + l15)) * 2048 + j0 + lq * 4;
    float rs = 0.f;
#pragma unroll
    for (int fn = 0; fn < 4; ++fn) {
      float4v sv = fn == 0 ? s0 : fn == 1 ? s1 : fn == 2 ? s2 : s3;
      short4v pk;
#pragma unroll
      for (int r = 0; r < 4; ++r) {
        u16 ev = f2bf(fexp2(sv[r]));
        pk[r] = (short)ev;
        rs += bf2f(ev);
      }
      *(short4v*)(eb + fn * 16) = pk;
    }
    rs += __shfl_xor(rs, 16);
    rs += __shfl_xor(rs, 32);
    if (l < 16)
      atomicAdd(lsum + (size_t)bh * 2048 + i_base + i0 + l, rs);
  }
}

// ------------------------ B: talk + head-LN (in place, R9 form) ------------
// grid (jchunk=4, iq=512, b=2), 256 threads. Thread owns 2 consecutive j at
// one (b,i): reads 16 h-planes (u32 each, wave-coalesced), p=E*inv_l,
// t=Wtalk.p (in-reg matvec), LN over g in-reg, y=z*gamma+beta -> bf16,
// written over E. p[32]+t[32] floats fits the 128-reg cap (4 waves/EU).
__global__ __launch_bounds__(256, 4) void talk_ln(u16* ey,
                                                  const float* __restrict__ lsum,
                                                  const float* __restrict__ wtalk,
                                                  const float* __restrict__ gamma,
                                                  const float* __restrict__ beta,
                                                  int i_base) {
  __shared__ float wt[256];
  __shared__ float invl[16], ga[16], be[16];
  const int tid = threadIdx.x;
  const int jc = blockIdx.x, iq = blockIdx.y, b = blockIdx.z;
  const int ig = i_base + iq;
  wt[tid] = wtalk[tid];
  if (tid < 16) {
    invl[tid] = 1.f / lsum[(size_t)(b * 16 + tid) * 2048 + ig];
    ga[tid] = gamma[tid];
    be[tid] = beta[tid];
  }
  __syncthreads();

  const int j = jc * 512 + tid * 2;
  const size_t base = ((size_t)(b * 16) * 512 + iq) * 2048 + j;
  const size_t hstride = (size_t)512 * 2048;

  float p0[16], p1[16];
#pragma unroll
  for (int h = 0; h < 16; ++h) {
    unsigned u = *(const unsigned*)(ey + base + h * hstride);
    float il = invl[h];
    p0[h] = bf2f((u16)(u & 0xffffu)) * il;
    p1[h] = bf2f((u16)(u >> 16)) * il;
  }
  float t0[16], t1[16];
#pragma unroll
  for (int g = 0; g < 16; ++g) { t0[g] = 0.f; t1[g] = 0.f; }
#pragma unroll
  for (int h = 0; h < 16; ++h) {
#pragma unroll
    for (int g = 0; g < 16; ++g) {
      float wv = wt[g * 16 + h];
      t0[g] += wv * p0[h];
      t1[g] += wv * p1[h];
    }
  }
  float mu0 = 0.f, mu1 = 0.f, ss0 = 0.f, ss1 = 0.f;
#pragma unroll
  for (int g = 0; g < 16; ++g) {
    mu0 += t0[g]; ss0 += t0[g] * t0[g];
    mu1 += t1[g]; ss1 += t1[g] * t1[g];
  }
  mu0 *= 0.0625f; mu1 *= 0.0625f;
  float rv0 = rsqrtf(ss0 * 0.0625f - mu0 * mu0 + 1e-5f);
  float rv1 = rsqrtf(ss1 * 0.0625f - mu1 * mu1 + 1e-5f);
#pragma unroll
  for (int g = 0; g < 16; ++g) {
    float y0 = (t0[g] - mu0) * rv0 * ga[g] + be[g];
    float y1 = (t1[g] - mu1) * rv1 * ga[g] + be[g];
    unsigned o = (unsigned)f2bf(y0) | ((unsigned)f2bf(y1) << 16);
    *(unsigned*)(ey + base + g * hstride) = o;
  }
}

// ------------------------ C: PV GEMM (out = Y . V^T, BK=64) ----------------
// grid (itile=8, bg=32) per quarter. A=Y (K=j contiguous), W=V^T, K=2048,
// 32 k-steps of 64, f32 direct stores.
__global__ __launch_bounds__(256, 4) void pv_gemm(const u16* __restrict__ Y,
                                                  const u16* __restrict__ VT,
                                                  float* __restrict__ out,
                                                  int i_base) {
  __shared__ u16 As[64][72];
  __shared__ u16 Ws[64][72];
  const int t = threadIdx.x;
  const int wave = t >> 6, l = t & 63, l15 = l & 15, lq = l >> 4;
  const int r0 = blockIdx.x * 64;
  const int bg = blockIdx.y;
  const int srow = t >> 2, sch = t & 3;
  const u16* ag = Y + ((size_t)bg * 512 + r0 + srow) * 2048 + sch * 16;
  const u16* wg = VT + ((size_t)bg * 64 + srow) * 2048 + sch * 16;

  float4v acc[4];
#pragma unroll
  for (int i = 0; i < 4; ++i) acc[i] = (float4v){0.f, 0.f, 0.f, 0.f};

  short8 av0 = *(const short8*)ag, av1 = *(const short8*)(ag + 8);
  short8 wv0 = *(const short8*)wg, wv1 = *(const short8*)(wg + 8);
  for (int kt = 0; kt < 32; ++kt) {
    __syncthreads();
    *(short8*)&As[srow][sch * 16] = av0;
    *(short8*)&As[srow][sch * 16 + 8] = av1;
    *(short8*)&Ws[srow][sch * 16] = wv0;
    *(short8*)&Ws[srow][sch * 16 + 8] = wv1;
    __syncthreads();
    if (kt < 31) {
      const u16* an = ag + (kt + 1) * 64;
      const u16* wn = wg + (kt + 1) * 64;
      av0 = *(const short8*)an; av1 = *(const short8*)(an + 8);
      wv0 = *(const short8*)wn; wv1 = *(const short8*)(wn + 8);
    }
    short8 af0 = *(const short8*)&As[wave * 16 + l15][lq * 8];
    short8 af1 = *(const short8*)&As[wave * 16 + l15][32 + lq * 8];
#pragma unroll
    for (int fn = 0; fn < 4; ++fn) {
      short8 bf0 = *(const short8*)&Ws[fn * 16 + l15][lq * 8];
      short8 bf1 = *(const short8*)&Ws[fn * 16 + l15][32 + lq * 8];
      acc[fn] = MFMA16(af0, bf0, acc[fn]);
      acc[fn] = MFMA16(af1, bf1, acc[fn]);
    }
  }
  const int b = bg >> 4, g = bg & 15;
#pragma unroll
  for (int fn = 0; fn < 4; ++fn) {
#pragma unroll
    for (int r = 0; r < 4; ++r) {
      int row = i_base + r0 + wave * 16 + lq * 4 + r;
      int col = g * 64 + fn * 16 + l15;
      out[((size_t)b * 2048 + row) * 1024 + col] = acc[fn][r];
    }
  }
}

// ----------------------------- launcher ------------------------------------
extern "C" void kernel_launch(void* const* d_in, const int* in_sizes, int n_in,
                              void* d_out, int out_size, void* d_ws,
                              size_t ws_size, hipStream_t stream) {
  const float* x = (const float*)d_in[0];
  const float* ctx = (const float*)d_in[1];
  const float* Wq = (const float*)d_in[2];
  const float* Wkv = (const float*)d_in[3];
  const float* Wtalk = (const float*)d_in[4];
  const float* gam = (const float*)d_in[5];
  const float* bet = (const float*)d_in[6];
  float* out = (float*)d_out;

  // persistent region (alive across the whole pipeline)
  u16* ws = (u16*)d_ws;
  u16* qhb = ws;                   // 4 Mi elems  [b][h][n][64]
  u16* khb = ws + 4194304;         // 4 Mi        [b][h][j][64]
  u16* vtb = ws + 8388608;         // 4 Mi        [b][h][d][2048]
  float* lsum = (float*)(ws + 12582912);  // 64 Ki f32
  // scratch region: cast/proj temporaries, later overlaid by E (32 Mi elems)
  u16* scr = ws + 12845056;
  u16* xb = scr;                   // 4 Mi
  u16* cb = scr + 4194304;         // 4 Mi
  u16* wqb = scr + 8388608;        // 1 Mi
  u16* wkvb = scr + 9437184;       // 2 Mi
  u16* vhb = scr + 11534336;       // 4 Mi
  u16* E = scr;                    // 32 Mi elems (64 MB), per-quarter reuse

  hipMemsetAsync(lsum, 0, 65536 * sizeof(float), stream);

  cast_bf16<<<2048, 256, 0, stream>>>(x, xb, 4194304);
  cast_bf16<<<2048, 256, 0, stream>>>(ctx, cb, 4194304);
  cast_bf16<<<512, 256, 0, stream>>>(Wq, wqb, 1048576);
  cast_bf16<<<1024, 256, 0, stream>>>(Wkv, wkvb, 2097152);

  gemm_bt<0><<<dim3(64, 16), 256, 0, stream>>>(xb, wqb, qhb, nullptr);
  gemm_bt<1><<<dim3(64, 32), 256, 0, stream>>>(cb, wkvb, khb, vhb);

  transpose_v<<<dim3(32, 16, 2), 256, 0, stream>>>(vhb, vtb);

  for (int q = 0; q < 4; ++q) {
    int i_base = q * 512;
    qk_exp<<<dim3(8, 8, 32), 256, 0, stream>>>(qhb, khb, E, lsum, i_base);
    talk_ln<<<dim3(4, 512, 2), 256, 0, stream>>>(E, lsum, Wtalk, gam, bet,
                                                 i_base);
    pv_gemm<<<dim3(8, 32), 256, 0, stream>>>(E, vtb, out, i_base);
  }
}

// Round 8
// 556.134 us; speedup vs baseline: 1.7830x; 1.7830x over previous
//
#include <hip/hip_runtime.h>

// ---------------------------------------------------------------------------
// Talking-heads attention. B=2, N=M=2048, D=1024, H=16, dh=64.
// R12: R11 with (a) talk_ln restored to the EXACT R9 no-spill shape — bare
// __launch_bounds__(256); min-waves bounds provably trigger scratch placement
// of the unrolled p/t arrays on this toolchain (R10 (,5) and R11 (,4) both
// spilled, R9 bare did not) — and (b) E re-laid out as [b][i][h][j] so all
// 16 h-planes of one (b,i) sit in one 64KB chunk (plane stride 4KB, was 2MB).
// ---------------------------------------------------------------------------

typedef __attribute__((ext_vector_type(8))) short short8;
typedef __attribute__((ext_vector_type(4))) short short4v;
typedef __attribute__((ext_vector_type(4))) float float4v;
typedef unsigned short u16;

#define MFMA16(a, b, c) __builtin_amdgcn_mfma_f32_16x16x32_bf16((a), (b), (c), 0, 0, 0)

__device__ inline u16 f2bf(float f) {  // RNE f32->bf16 (inputs finite)
  unsigned u = __float_as_uint(f);
  u += 0x7FFFu + ((u >> 16) & 1u);
  return (u16)(u >> 16);
}
__device__ inline float bf2f(u16 u) {
  return __uint_as_float(((unsigned)u) << 16);
}
__device__ inline float fexp2(float x) { return __builtin_amdgcn_exp2f(x); }

// ---------------------------- cast kernel ----------------------------------
__global__ __launch_bounds__(256) void cast_bf16(const float* __restrict__ in,
                                                 u16* __restrict__ out, int n) {
  int i = (blockIdx.x * 256 + threadIdx.x) * 8;
  if (i + 8 > n) return;
  float4v f0 = *(const float4v*)(in + i);
  float4v f1 = *(const float4v*)(in + i + 4);
  short8 o;
  o[0] = (short)f2bf(f0[0]); o[1] = (short)f2bf(f0[1]);
  o[2] = (short)f2bf(f0[2]); o[3] = (short)f2bf(f0[3]);
  o[4] = (short)f2bf(f1[0]); o[5] = (short)f2bf(f1[1]);
  o[6] = (short)f2bf(f1[2]); o[7] = (short)f2bf(f1[3]);
  *(short8*)(out + i) = o;
}

// ------------------------ projection GEMM (BK=64) --------------------------
template <int MODE>
__global__ __launch_bounds__(256, 4) void gemm_bt(const u16* __restrict__ A,
                                                  const u16* __restrict__ W,
                                                  u16* __restrict__ out0,
                                                  u16* __restrict__ out1) {
  __shared__ u16 As[64][72];
  __shared__ u16 Ws[64][72];
  const int t = threadIdx.x;
  const int wave = t >> 6, l = t & 63, l15 = l & 15, lq = l >> 4;
  const int r0 = blockIdx.x * 64, c0 = blockIdx.y * 64;
  const int srow = t >> 2, sch = t & 3;
  const u16* ag = A + (r0 + srow) * 1024 + sch * 16;
  const u16* wg = W + (c0 + srow) * 1024 + sch * 16;

  float4v acc[4];
#pragma unroll
  for (int i = 0; i < 4; ++i) acc[i] = (float4v){0.f, 0.f, 0.f, 0.f};

  short8 av0 = *(const short8*)ag, av1 = *(const short8*)(ag + 8);
  short8 wv0 = *(const short8*)wg, wv1 = *(const short8*)(wg + 8);
  for (int kt = 0; kt < 16; ++kt) {
    __syncthreads();
    *(short8*)&As[srow][sch * 16] = av0;
    *(short8*)&As[srow][sch * 16 + 8] = av1;
    *(short8*)&Ws[srow][sch * 16] = wv0;
    *(short8*)&Ws[srow][sch * 16 + 8] = wv1;
    __syncthreads();
    if (kt < 15) {
      const u16* an = ag + (kt + 1) * 64;
      const u16* wn = wg + (kt + 1) * 64;
      av0 = *(const short8*)an; av1 = *(const short8*)(an + 8);
      wv0 = *(const short8*)wn; wv1 = *(const short8*)(wn + 8);
    }
    short8 af0 = *(const short8*)&As[wave * 16 + l15][lq * 8];
    short8 af1 = *(const short8*)&As[wave * 16 + l15][32 + lq * 8];
#pragma unroll
    for (int fn = 0; fn < 4; ++fn) {
      short8 bf0 = *(const short8*)&Ws[fn * 16 + l15][lq * 8];
      short8 bf1 = *(const short8*)&Ws[fn * 16 + l15][32 + lq * 8];
      acc[fn] = MFMA16(af0, bf0, acc[fn]);
      acc[fn] = MFMA16(af1, bf1, acc[fn]);
    }
  }
#pragma unroll
  for (int fn = 0; fn < 4; ++fn) {
#pragma unroll
    for (int r = 0; r < 4; ++r) {
      int row = r0 + wave * 16 + lq * 4 + r;
      int col = c0 + fn * 16 + l15;
      int b = row >> 11, n = row & 2047;
      float v = acc[fn][r];
      if (MODE == 0) {
        // dh^-0.5 * log2(e): softmax done in base 2 (v_exp_f32 is 2^x)
        v *= 0.125f * 1.44269504088896f;
        int h = col >> 6, d = col & 63;
        out0[(((b * 16 + h) * 2048 + n) << 6) + d] = f2bf(v);
      } else {
        if (col < 1024) {
          int h = col >> 6, d = col & 63;
          out0[(((b * 16 + h) * 2048 + n) << 6) + d] = f2bf(v);
        } else {
          int cc = col - 1024;
          int h = cc >> 6, d = cc & 63;
          out1[(((b * 16 + h) * 2048 + n) << 6) + d] = f2bf(v);
        }
      }
    }
  }
}

// --------------------------- V transpose -----------------------------------
__global__ __launch_bounds__(256) void transpose_v(const u16* __restrict__ vh,
                                                   u16* __restrict__ vt) {
  __shared__ u16 tile[64][72];
  const int t = threadIdx.x;
  const int j0 = blockIdx.x * 64, h = blockIdx.y, b = blockIdx.z;
  const u16* src = vh + (((b * 16 + h) * 2048 + j0) << 6);
  int row = t >> 2, c = t & 3;
  short8 v0 = *(const short8*)(src + row * 64 + c * 8);
  short8 v1 = *(const short8*)(src + row * 64 + (c + 4) * 8);
  *(short8*)&tile[row][c * 8] = v0;
  *(short8*)&tile[row][(c + 4) * 8] = v1;
  __syncthreads();
  int d = t >> 2, jc = t & 3;
  short8 o0, o1;
#pragma unroll
  for (int jj = 0; jj < 8; ++jj) o0[jj] = (short)tile[jc * 16 + jj][d];
#pragma unroll
  for (int jj = 0; jj < 8; ++jj) o1[jj] = (short)tile[jc * 16 + 8 + jj][d];
  u16* dst = vt + ((b * 16 + h) * 64 + d) * 2048 + j0 + jc * 16;
  *(short8*)dst = o0;
  *(short8*)(dst + 8) = o1;
}

// ------------------------ A: QK^T -> E = 2^S -------------------------------
// grid (ib=8, jm=8, bh=32) per quarter, 256 threads (4 waves).
// Wave owns a 64-j strip: K fragments loaded ONCE into 32 VGPRs, loops 4
// i-subtiles of 16 rows. E layout [b][i][h][j] (plane stride 4KB).
// Row sums (of bf16-rounded E) atomicAdd'ed to lsum.
__global__ __launch_bounds__(256, 6) void qk_exp(const u16* __restrict__ qh,
                                                 const u16* __restrict__ kh,
                                                 u16* __restrict__ E,
                                                 float* __restrict__ lsum,
                                                 int i_base) {
  const int t = threadIdx.x;
  const int w = t >> 6, l = t & 63, l15 = l & 15, lq = l >> 4;
  const int ib = blockIdx.x;   // i-group of 64 (quarter-local)
  const int jm = blockIdx.y;   // j-macro of 256
  const int bh = blockIdx.z;
  const int b = bh >> 4, h = bh & 15;
  const int j0 = jm * 256 + w * 64;  // wave's j strip

  const u16* kb = kh + (size_t)(bh * 2048 + j0 + l15) * 64 + lq * 8;
  short8 k0 = *(const short8*)(kb);
  short8 k1 = *(const short8*)(kb + 32);
  short8 k2 = *(const short8*)(kb + 1024);
  short8 k3 = *(const short8*)(kb + 1024 + 32);
  short8 k4 = *(const short8*)(kb + 2048);
  short8 k5 = *(const short8*)(kb + 2048 + 32);
  short8 k6 = *(const short8*)(kb + 3072);
  short8 k7 = *(const short8*)(kb + 3072 + 32);

#pragma unroll 1
  for (int is = 0; is < 4; ++is) {
    const int i0 = ib * 64 + is * 16;  // quarter-local i of this subtile
    const u16* qb = qh + (size_t)(bh * 2048 + i_base + i0 + l15) * 64 + lq * 8;
    short8 qf0 = *(const short8*)qb;
    short8 qf1 = *(const short8*)(qb + 32);
    float4v s0 = {0.f, 0.f, 0.f, 0.f}, s1 = s0, s2 = s0, s3 = s0;
    s0 = MFMA16(k0, qf0, s0); s0 = MFMA16(k1, qf1, s0);
    s1 = MFMA16(k2, qf0, s1); s1 = MFMA16(k3, qf1, s1);
    s2 = MFMA16(k4, qf0, s2); s2 = MFMA16(k5, qf1, s2);
    s3 = MFMA16(k6, qf0, s3); s3 = MFMA16(k7, qf1, s3);
    // lane holds E[i = i0+l15][j = j0 + fn*16 + lq*4 + r], plane h
    u16* eb = E + (((size_t)(b * 512 + i0 + l15)) * 16 + h) * 2048 + j0 + lq * 4;
    float rs = 0.f;
#pragma unroll
    for (int fn = 0; fn < 4; ++fn) {
      float4v sv = fn == 0 ? s0 : fn == 1 ? s1 : fn == 2 ? s2 : s3;
      short4v pk;
#pragma unroll
      for (int r = 0; r < 4; ++r) {
        u16 ev = f2bf(fexp2(sv[r]));
        pk[r] = (short)ev;
        rs += bf2f(ev);
      }
      *(short4v*)(eb + fn * 16) = pk;
    }
    rs += __shfl_xor(rs, 16);
    rs += __shfl_xor(rs, 32);
    if (l < 16)
      atomicAdd(lsum + (size_t)bh * 2048 + i_base + i0 + l, rs);
  }
}

// ------------------------ B: talk + head-LN (in place, R9 shape) -----------
// grid (jchunk=4, iq=512, b=2), 256 threads, bare launch_bounds (NO min-waves
// arg: R10/R11 proved it scratch-spills the p/t arrays; R9 bare was clean).
// Thread owns 2 consecutive j at one (b,i): reads 16 h-planes (u32, stride
// 4KB, all within one 64KB chunk), p=E*inv_l, t=Wtalk.p in-reg, LN in-reg,
// y=z*gamma+beta -> bf16 written over E.
__global__ __launch_bounds__(256) void talk_ln(u16* ey,
                                               const float* __restrict__ lsum,
                                               const float* __restrict__ wtalk,
                                               const float* __restrict__ gamma,
                                               const float* __restrict__ beta,
                                               int i_base) {
  __shared__ float wt[256];
  __shared__ float invl[16], ga[16], be[16];
  const int tid = threadIdx.x;
  const int jc = blockIdx.x, iq = blockIdx.y, b = blockIdx.z;
  const int ig = i_base + iq;
  wt[tid] = wtalk[tid];
  if (tid < 16) {
    invl[tid] = 1.f / lsum[(size_t)(b * 16 + tid) * 2048 + ig];
    ga[tid] = gamma[tid];
    be[tid] = beta[tid];
  }
  __syncthreads();

  const int j = jc * 512 + tid * 2;
  const size_t base = ((size_t)(b * 512 + iq)) * 16 * 2048 + j;
  const size_t hstride = 2048;

  float p0[16], p1[16];
#pragma unroll
  for (int h = 0; h < 16; ++h) {
    unsigned u = *(const unsigned*)(ey + base + h * hstride);
    float il = invl[h];
    p0[h] = bf2f((u16)(u & 0xffffu)) * il;
    p1[h] = bf2f((u16)(u >> 16)) * il;
  }
  float t0[16], t1[16];
#pragma unroll
  for (int g = 0; g < 16; ++g) { t0[g] = 0.f; t1[g] = 0.f; }
#pragma unroll
  for (int h = 0; h < 16; ++h) {
#pragma unroll
    for (int g = 0; g < 16; ++g) {
      float wv = wt[g * 16 + h];
      t0[g] += wv * p0[h];
      t1[g] += wv * p1[h];
    }
  }
  float mu0 = 0.f, mu1 = 0.f, ss0 = 0.f, ss1 = 0.f;
#pragma unroll
  for (int g = 0; g < 16; ++g) {
    mu0 += t0[g]; ss0 += t0[g] * t0[g];
    mu1 += t1[g]; ss1 += t1[g] * t1[g];
  }
  mu0 *= 0.0625f; mu1 *= 0.0625f;
  float rv0 = rsqrtf(ss0 * 0.0625f - mu0 * mu0 + 1e-5f);
  float rv1 = rsqrtf(ss1 * 0.0625f - mu1 * mu1 + 1e-5f);
#pragma unroll
  for (int g = 0; g < 16; ++g) {
    float y0 = (t0[g] - mu0) * rv0 * ga[g] + be[g];
    float y1 = (t1[g] - mu1) * rv1 * ga[g] + be[g];
    unsigned o = (unsigned)f2bf(y0) | ((unsigned)f2bf(y1) << 16);
    *(unsigned*)(ey + base + g * hstride) = o;
  }
}

// ------------------------ C: PV GEMM (out = Y . V^T, BK=64) ----------------
// grid (itile=8, bg=32) per quarter. A=Y rows (b,i,g) with j contiguous
// (layout [b][i][g][j], row stride 16*2048), W=V^T, K=2048, f32 stores.
__global__ __launch_bounds__(256, 4) void pv_gemm(const u16* __restrict__ Y,
                                                  const u16* __restrict__ VT,
                                                  float* __restrict__ out,
                                                  int i_base) {
  __shared__ u16 As[64][72];
  __shared__ u16 Ws[64][72];
  const int t = threadIdx.x;
  const int wave = t >> 6, l = t & 63, l15 = l & 15, lq = l >> 4;
  const int r0 = blockIdx.x * 64;
  const int bg = blockIdx.y;
  const int b = bg >> 4, g = bg & 15;
  const int srow = t >> 2, sch = t & 3;
  const u16* ag = Y + (((size_t)(b * 512 + r0 + srow)) * 16 + g) * 2048 + sch * 16;
  const u16* wg = VT + ((size_t)bg * 64 + srow) * 2048 + sch * 16;

  float4v acc[4];
#pragma unroll
  for (int i = 0; i < 4; ++i) acc[i] = (float4v){0.f, 0.f, 0.f, 0.f};

  short8 av0 = *(const short8*)ag, av1 = *(const short8*)(ag + 8);
  short8 wv0 = *(const short8*)wg, wv1 = *(const short8*)(wg + 8);
  for (int kt = 0; kt < 32; ++kt) {
    __syncthreads();
    *(short8*)&As[srow][sch * 16] = av0;
    *(short8*)&As[srow][sch * 16 + 8] = av1;
    *(short8*)&Ws[srow][sch * 16] = wv0;
    *(short8*)&Ws[srow][sch * 16 + 8] = wv1;
    __syncthreads();
    if (kt < 31) {
      const u16* an = ag + (kt + 1) * 64;
      const u16* wn = wg + (kt + 1) * 64;
      av0 = *(const short8*)an; av1 = *(const short8*)(an + 8);
      wv0 = *(const short8*)wn; wv1 = *(const short8*)(wn + 8);
    }
    short8 af0 = *(const short8*)&As[wave * 16 + l15][lq * 8];
    short8 af1 = *(const short8*)&As[wave * 16 + l15][32 + lq * 8];
#pragma unroll
    for (int fn = 0; fn < 4; ++fn) {
      short8 bf0 = *(const short8*)&Ws[fn * 16 + l15][lq * 8];
      short8 bf1 = *(const short8*)&Ws[fn * 16 + l15][32 + lq * 8];
      acc[fn] = MFMA16(af0, bf0, acc[fn]);
      acc[fn] = MFMA16(af1, bf1, acc[fn]);
    }
  }
#pragma unroll
  for (int fn = 0; fn < 4; ++fn) {
#pragma unroll
    for (int r = 0; r < 4; ++r) {
      int row = i_base + r0 + wave * 16 + lq * 4 + r;
      int col = g * 64 + fn * 16 + l15;
      out[((size_t)b * 2048 + row) * 1024 + col] = acc[fn][r];
    }
  }
}

// ----------------------------- launcher ------------------------------------
extern "C" void kernel_launch(void* const* d_in, const int* in_sizes, int n_in,
                              void* d_out, int out_size, void* d_ws,
                              size_t ws_size, hipStream_t stream) {
  const float* x = (const float*)d_in[0];
  const float* ctx = (const float*)d_in[1];
  const float* Wq = (const float*)d_in[2];
  const float* Wkv = (const float*)d_in[3];
  const float* Wtalk = (const float*)d_in[4];
  const float* gam = (const float*)d_in[5];
  const float* bet = (const float*)d_in[6];
  float* out = (float*)d_out;

  // persistent region (alive across the whole pipeline)
  u16* ws = (u16*)d_ws;
  u16* qhb = ws;                   // 4 Mi elems  [b][h][n][64]
  u16* khb = ws + 4194304;         // 4 Mi        [b][h][j][64]
  u16* vtb = ws + 8388608;         // 4 Mi        [b][h][d][2048]
  float* lsum = (float*)(ws + 12582912);  // 64 Ki f32
  // scratch region: cast/proj temporaries, later overlaid by E (32 Mi elems)
  u16* scr = ws + 12845056;
  u16* xb = scr;                   // 4 Mi
  u16* cb = scr + 4194304;         // 4 Mi
  u16* wqb = scr + 8388608;        // 1 Mi
  u16* wkvb = scr + 9437184;       // 2 Mi
  u16* vhb = scr + 11534336;       // 4 Mi
  u16* E = scr;                    // 32 Mi elems (64 MB), per-quarter reuse

  hipMemsetAsync(lsum, 0, 65536 * sizeof(float), stream);

  cast_bf16<<<2048, 256, 0, stream>>>(x, xb, 4194304);
  cast_bf16<<<2048, 256, 0, stream>>>(ctx, cb, 4194304);
  cast_bf16<<<512, 256, 0, stream>>>(Wq, wqb, 1048576);
  cast_bf16<<<1024, 256, 0, stream>>>(Wkv, wkvb, 2097152);

  gemm_bt<0><<<dim3(64, 16), 256, 0, stream>>>(xb, wqb, qhb, nullptr);
  gemm_bt<1><<<dim3(64, 32), 256, 0, stream>>>(cb, wkvb, khb, vhb);

  transpose_v<<<dim3(32, 16, 2), 256, 0, stream>>>(vhb, vtb);

  for (int q = 0; q < 4; ++q) {
    int i_base = q * 512;
    qk_exp<<<dim3(8, 8, 32), 256, 0, stream>>>(qhb, khb, E, lsum, i_base);
    talk_ln<<<dim3(4, 512, 2), 256, 0, stream>>>(E, lsum, Wtalk, gam, bet,
                                                 i_base);
    pv_gemm<<<dim3(8, 32), 256, 0, stream>>>(E, vtb, out, i_base);
  }
}